// Round 6
// baseline (286.228 us; speedup 1.0000x reference)
//
#include <hip/hip_runtime.h>
#include <hip/hip_bf16.h>
#include <stdint.h>

// Problem constants
#define H_    16
#define N_    2048
#define DIM_  1024
#define DH_   64
#define NN_   2
#define J_    2050     // N + NNULL
#define JP_   2112     // 33*64, padded j (Kb zero tail via memset, VTp zero-filled)
#define B_    2
#define M_    4096     // B * N
#define NSEG_ 84       // sum over qt of ceil((qt+2)/8)

typedef unsigned short u16;
typedef unsigned int u32;
typedef short bf16x8 __attribute__((ext_vector_type(8)));
typedef float f32x4 __attribute__((ext_vector_type(4)));

__device__ __forceinline__ u16 f2b(float f) {
  union { float f; unsigned int i; } v; v.f = f;
  unsigned int r = v.i + 0x7fffu + ((v.i >> 16) & 1u);   // RNE
  return (u16)(r >> 16);
}
__device__ __forceinline__ float b2f(u16 u) {
  union { unsigned int i; float f; } v; v.i = ((unsigned int)u) << 16; return v.f;
}
__device__ __forceinline__ float lo2f(u32 u) {
  union { u32 i; float f; } v; v.i = u << 16; return v.f;
}
__device__ __forceinline__ float hi2f(u32 u) {
  union { u32 i; float f; } v; v.i = u & 0xffff0000u; return v.f;
}
__device__ __forceinline__ void unp8(const uint4 u, float* d) {
  d[0] = lo2f(u.x); d[1] = hi2f(u.x); d[2] = lo2f(u.y); d[3] = hi2f(u.y);
  d[4] = lo2f(u.z); d[5] = hi2f(u.z); d[6] = lo2f(u.w); d[7] = hi2f(u.w);
}
// packed fp32x2 -> bf16x2 (v_cvt_pk_bf16_f32 on gfx950 via HIP API)
__device__ __forceinline__ u32 pk2(float a, float b) {
  union { __hip_bfloat162 h; u32 u; } x;
  x.h = __float22bfloat162_rn(make_float2(a, b));
  return x.u;
}
// async global->LDS DMA, 16B/lane; LDS dest = wave-uniform base + lane*16
__device__ __forceinline__ void dma16(const u16* g, u16* l) {
  __builtin_amdgcn_global_load_lds(
      (const __attribute__((address_space(1))) u32*)(const void*)g,
      (__attribute__((address_space(3))) u32*)(void*)l, 16, 0, 0);
}

// ---------------- transpose + cast (fp32 R x C -> bf16 C x R) ----------------
__global__ __launch_bounds__(256) void ktranspose_cast(const float* __restrict__ in,
                                                       u16* __restrict__ out, int R, int C) {
  __shared__ float tile[32][33];
  int tx = threadIdx.x & 31, ty = threadIdx.x >> 5;   // 32 x 8
  int c0 = blockIdx.x * 32, r0 = blockIdx.y * 32;
  #pragma unroll
  for (int i = 0; i < 32; i += 8)
    tile[ty + i][tx] = in[(size_t)(r0 + ty + i) * C + c0 + tx];
  __syncthreads();
  #pragma unroll
  for (int i = 0; i < 32; i += 8)
    out[(size_t)(c0 + ty + i) * R + r0 + tx] = f2b(tile[tx][ty + i]);
}

// ---------- LayerNorm (fp32 in) -> xn (bf16 LN) + xbf (bf16 cast of x) ----------
__global__ __launch_bounds__(256) void lnorm_k(const float* __restrict__ x,
                                               const float* __restrict__ g,
                                               const float* __restrict__ bb,
                                               u16* __restrict__ xn,
                                               u16* __restrict__ xbf) {
  int row = blockIdx.x;
  int t = threadIdx.x;
  float4 rw = *(const float4*)(x + (size_t)row * DIM_ + t * 4);
  float v0 = rw.x, v1 = rw.y, v2 = rw.z, v3 = rw.w;
  uint2 cw;
  cw.x = pk2(v0, v1);
  cw.y = pk2(v2, v3);
  *(uint2*)(xbf + (size_t)row * DIM_ + t * 4) = cw;
  float s = v0 + v1 + v2 + v3;
  float ss = v0 * v0 + v1 * v1 + v2 * v2 + v3 * v3;
  #pragma unroll
  for (int o = 32; o; o >>= 1) { s += __shfl_xor(s, o, 64); ss += __shfl_xor(ss, o, 64); }
  __shared__ float red[8];
  int lane = t & 63, w = t >> 6;
  if (lane == 0) { red[w] = s; red[4 + w] = ss; }
  __syncthreads();
  float S = red[0] + red[1] + red[2] + red[3];
  float SS = red[4] + red[5] + red[6] + red[7];
  float mu = S * (1.0f / DIM_);
  float var = SS * (1.0f / DIM_) - mu * mu;
  float rs = rsqrtf(var + 1e-5f);
  float4 gv = *(const float4*)(g + t * 4);
  float4 bv = *(const float4*)(bb + t * 4);
  uint2 ow;
  ow.x = pk2((v0 - mu) * rs * gv.x + bv.x, (v1 - mu) * rs * gv.y + bv.y);
  ow.y = pk2((v2 - mu) * rs * gv.z + bv.z, (v3 - mu) * rs * gv.w + bv.w);
  *(uint2*)(xn + (size_t)row * DIM_ + t * 4) = ow;
}

// ------------- MFMA GEMM, m97 structure: 128x128 tile, 4 waves x 64x64 -------------
// MODE 1: fp32 row-major -> dst0
// MODE 2: per-row l2norm over 64-col head * (8*qs) -> Qn (b,h,n,d)   [SCALE folded in]
// MODE 3: cols<1024: l2norm*ks -> Kb (b,h,j=n+2,d) stride JP; else bf16 -> Vb stride J
template <int MODE>
__global__ __launch_bounds__(256) void gemm_k(const u16* __restrict__ A,
                                              const u16* __restrict__ BT,
                                              void* __restrict__ dst0,
                                              void* __restrict__ dst1,
                                              const float* __restrict__ scale,
                                              int M, int Nc, int K) {
  __shared__ u16 As[128 * 32];   // unpadded (global_load_lds lane mapping)
  __shared__ u16 Bs[128 * 32];
  int tid = threadIdx.x, wv = tid >> 6, lane = tid & 63;
  int fm = lane & 15, fg = lane >> 4;
  int row0 = blockIdx.y * 128, col0 = blockIdx.x * 128;
  int wr = (wv & 1) * 64, wc = (wv >> 1) * 64;
  f32x4 acc[4][4] = {};
  int lr = lane >> 2, lc8 = (lane & 3) * 8;
  const u16* Ag = A + (size_t)(row0 + wv * 32 + lr) * K + lc8;
  const u16* Bg = BT + (size_t)(col0 + wv * 32 + lr) * K + lc8;
  u16* AsW = As + wv * 1024;   // wave stages A rows [wv*32, wv*32+32)
  u16* BsW = Bs + wv * 1024;
  for (int k0 = 0; k0 < K; k0 += 32) {
    __syncthreads();
    dma16(Ag + k0, AsW);
    dma16(Ag + (size_t)16 * K + k0, AsW + 512);
    dma16(Bg + k0, BsW);
    dma16(Bg + (size_t)16 * K + k0, BsW + 512);
    __syncthreads();
    bf16x8 af[4], bfv[4];
    #pragma unroll
    for (int mt = 0; mt < 4; mt++)
      af[mt] = *(const bf16x8*)&As[(wr + mt * 16 + fm) * 32 + fg * 8];
    #pragma unroll
    for (int nt = 0; nt < 4; nt++)
      bfv[nt] = *(const bf16x8*)&Bs[(wc + nt * 16 + fm) * 32 + fg * 8];
    #pragma unroll
    for (int mt = 0; mt < 4; mt++)
      #pragma unroll
      for (int nt = 0; nt < 4; nt++)
        acc[mt][nt] = __builtin_amdgcn_mfma_f32_16x16x32_bf16(af[mt], bfv[nt], acc[mt][nt], 0, 0, 0);
  }
  // C/D layout per 16x16 tile: col = fm, row = fg*4 + r
  if (MODE == 1) {
    float* C = (float*)dst0;
    #pragma unroll
    for (int mt = 0; mt < 4; mt++)
      #pragma unroll
      for (int r = 0; r < 4; r++) {
        int m = row0 + wr + mt * 16 + fg * 4 + r;
        #pragma unroll
        for (int nt = 0; nt < 4; nt++)
          C[(size_t)m * Nc + col0 + wc + nt * 16 + fm] = acc[mt][nt][r];
      }
  } else {
    int cb = col0 + wc;                       // wave's 64-col base = one head
    bool isK = (MODE == 2) || (cb < 1024);
    int h = (isK ? cb : cb - 1024) >> 6;
    float sv[4];
    if (isK) {
      float mul = (MODE == 2) ? 8.0f : 1.0f;  // fold attention SCALE into Qn
      #pragma unroll
      for (int nt = 0; nt < 4; nt++) sv[nt] = scale[nt * 16 + fm] * mul;
    }
    u16* Do = (u16*)((MODE == 3 && !isK) ? dst1 : dst0);
    #pragma unroll
    for (int mt = 0; mt < 4; mt++) {
      #pragma unroll
      for (int r = 0; r < 4; r++) {
        float inv = 1.0f;
        if (isK) {
          float ssp = 0.0f;
          #pragma unroll
          for (int nt = 0; nt < 4; nt++) ssp += acc[mt][nt][r] * acc[mt][nt][r];
          #pragma unroll
          for (int o = 1; o <= 8; o <<= 1) ssp += __shfl_xor(ssp, o, 64);
          inv = 1.0f / fmaxf(sqrtf(ssp), 1e-12f);
        }
        int m = row0 + wr + mt * 16 + fg * 4 + r;
        int b = m >> 11, n = m & 2047;
        size_t base;
        if (MODE == 2)      base = (((size_t)(b * H_ + h)) * N_ + n) * 64;
        else if (isK)       base = (((size_t)(b * H_ + h)) * JP_ + (n + NN_)) * 64;
        else                base = (((size_t)(b * H_ + h)) * J_ + (n + NN_)) * 64;
        #pragma unroll
        for (int nt = 0; nt < 4; nt++) {
          float val = acc[mt][nt][r];
          if (isK) val = val * inv * sv[nt];
          Do[base + nt * 16 + fm] = f2b(val);
        }
      }
    }
  }
}

// ------- V transpose+permute: Vb (b,h,j,d) + null kv -> VTp (b,h,d,pos); also Kb j<2 -------
// VTp[bh][d][c*64+pos] = V[bh][c*64 + pi(pos)][d],
// pi(pos): h2=pos>>5, fgp=(pos>>3)&3, nt=(pos>>2)&1, r=pos&3 -> j = (h2*2+nt)*16 + fgp*4 + r
__global__ __launch_bounds__(256) void vtransp_k(const u16* __restrict__ Vb,
                                                 const float* __restrict__ nkv,
                                                 const float* __restrict__ ks,
                                                 u16* __restrict__ Kb,
                                                 u16* __restrict__ VTp) {
  __shared__ u16 tile[64][80];
  int t = threadIdx.x;
  int c = blockIdx.x, bh = blockIdx.y, h = bh & 15;
  int jl = t >> 2, dc = (t & 3) * 16;
  int j = c * 64 + jl;
  if (j < NN_) {
    float kvv[16];
    float kssp = 0.0f;
    #pragma unroll
    for (int e = 0; e < 16; e++) {
      float vv = nkv[(size_t)(h * 4 + 2 * j + 1) * 64 + dc + e];
      tile[jl][dc + e] = f2b(vv);
      float kv = nkv[(size_t)(h * 4 + 2 * j) * 64 + dc + e];
      kvv[e] = kv; kssp += kv * kv;
    }
    kssp += __shfl_xor(kssp, 1, 64);
    kssp += __shfl_xor(kssp, 2, 64);
    float inv = 1.0f / fmaxf(sqrtf(kssp), 1e-12f);
    #pragma unroll
    for (int e = 0; e < 16; e++)
      Kb[((size_t)bh * JP_ + j) * 64 + dc + e] = f2b(kvv[e] * inv * ks[dc + e]);
  } else if (j < J_) {
    const uint4* src = (const uint4*)(Vb + ((size_t)bh * J_ + j) * 64 + dc);
    *(uint4*)&tile[jl][dc] = src[0];
    *(uint4*)&tile[jl][dc + 8] = src[1];
  } else {
    uint4 z = {0, 0, 0, 0};
    *(uint4*)&tile[jl][dc] = z;
    *(uint4*)&tile[jl][dc + 8] = z;
  }
  __syncthreads();
  int d = t >> 2, p0 = (t & 3) * 16;
  u16 tmp[16] __attribute__((aligned(16)));
  #pragma unroll
  for (int e = 0; e < 16; e++) {
    int pos = p0 + e;
    int h2 = pos >> 5, rem = pos & 31;
    int fgp = rem >> 3, tt = rem & 7;
    int nt = tt >> 2, r = tt & 3;
    int jloc = (h2 * 2 + nt) * 16 + fgp * 4 + r;
    tmp[e] = tile[jloc][d];
  }
  uint4* dstp = (uint4*)(VTp + ((size_t)bh * 64 + d) * JP_ + c * 64 + p0);
  dstp[0] = ((uint4*)tmp)[0];
  dstp[1] = ((uint4*)tmp)[1];
}

// ---------------- MFMA flash attention, j-SPLIT partial blocks ----------------
// Qn carries 8*qs (SCALE folded). Fixed-cap softmax; partial (O bf16, l fp32) per slot.
__global__ __launch_bounds__(256, 6) void attn_k(const u16* __restrict__ Qn,
                                                 const u16* __restrict__ Kb,
                                                 const u16* __restrict__ VTp,
                                                 const float* __restrict__ qs,
                                                 const float* __restrict__ ks,
                                                 u16* __restrict__ partials) {
  __shared__ u16 Ks0[64 * 32], Ks1[64 * 32];   // K chunk rows j, d 0..31 / 32..63
  __shared__ u16 Vs0[64 * 32], Vs1[64 * 32];   // V^T chunk rows d, j-pos 0..31 / 32..63
  int tid = threadIdx.x;
  int wv = tid >> 6, lane = tid & 63;
  int fm = lane & 15, fg = lane >> 4;
  int bh = blockIdx.y, h = bh & 15;
  // segment decode (qt descending)
  int cum = 0, qt = 0, seg = 0;
  #pragma unroll 1
  for (int i = 0; i < 32; i++) {
    int t = 31 - i, s = (t + 9) >> 3;
    if ((int)blockIdx.x < cum + s) { qt = t; seg = (int)blockIdx.x - cum; break; }
    cum += s;
  }
  int q0 = qt * 64;
  int q = q0 + wv * 16 + fm;
  float slope = exp2f(-0.5f * (float)(h + 1));
  float prod = fabsf(qs[lane] * ks[lane]);
  #pragma unroll
  for (int o = 32; o; o >>= 1) prod = fmaxf(prod, __shfl_xor(prod, o, 64));
  float Mb = 8.0f * prod;
  // per-lane ALiBi offsets for the 16 in-chunk positions
  float boff[4][4];
  #pragma unroll
  for (int nt = 0; nt < 4; nt++)
    #pragma unroll
    for (int r = 0; r < 4; r++)
      boff[nt][r] = slope * (float)(nt * 16 + fg * 4 + r);
  const u16* qp = Qn + ((size_t)bh * N_ + q) * 64 + fg * 8;
  bf16x8 qf0 = *(const bf16x8*)(qp);        // d 0..31 slice
  bf16x8 qf1 = *(const bf16x8*)(qp + 32);   // d 32..63 slice
  f32x4 accO[4] = {};
  float lp = 0.0f;
  int lr = lane >> 2, lc8 = (lane & 3) * 8;
  const u16* KbBH = Kb + (size_t)bh * JP_ * 64;
  const u16* VTbh = VTp + (size_t)bh * 64 * JP_;
  int c0 = seg * 8;
  int c1 = min(c0 + 8, qt + 2);
  for (int c = c0; c < c1; c++) {
    int jb = c * 64;
    __syncthreads();
    const u16* Kg = KbBH + (size_t)jb * 64 + (size_t)(wv * 16 + lr) * 64 + lc8;
    dma16(Kg,      Ks0 + wv * 512);
    dma16(Kg + 32, Ks1 + wv * 512);
    const u16* Vg = VTbh + (size_t)(wv * 16 + lr) * JP_ + jb + lc8;
    dma16(Vg,      Vs0 + wv * 512);
    dma16(Vg + 32, Vs1 + wv * 512);
    __syncthreads();
    // S^T = K Q^T  (scores already x8 via Qn)
    f32x4 accS[4] = {};
    #pragma unroll
    for (int nt = 0; nt < 4; nt++) {
      bf16x8 kf0 = *(const bf16x8*)&Ks0[(nt * 16 + fm) * 32 + fg * 8];
      accS[nt] = __builtin_amdgcn_mfma_f32_16x16x32_bf16(kf0, qf0, accS[nt], 0, 0, 0);
      bf16x8 kf1 = *(const bf16x8*)&Ks1[(nt * 16 + fm) * 32 + fg * 8];
      accS[nt] = __builtin_amdgcn_mfma_f32_16x16x32_bf16(kf1, qf1, accS[nt], 0, 0, 0);
    }
    // softmax in-register
    float bias0 = slope * (float)(jb - q - 2) - Mb;
    bool full = (jb + 61 <= q0 + wv * 16);    // wave-uniform: chunk fully visible
    union { bf16x8 v; u32 u[4]; } P0, P1;
    float lt = 0.0f;
    if (full) {
      #pragma unroll
      for (int nt = 0; nt < 4; nt++) {
        float p[4];
        #pragma unroll
        for (int r = 0; r < 4; r++)
          p[r] = __expf((accS[nt][r] + boff[nt][r]) + bias0);
        lt += (p[0] + p[1]) + (p[2] + p[3]);
        u32 w0 = pk2(p[0], p[1]), w1 = pk2(p[2], p[3]);
        if (nt < 2) { P0.u[nt * 2] = w0; P0.u[nt * 2 + 1] = w1; }
        else        { P1.u[(nt - 2) * 2] = w0; P1.u[(nt - 2) * 2 + 1] = w1; }
      }
    } else {
      int lim = q + 2 - jb;
      #pragma unroll
      for (int nt = 0; nt < 4; nt++) {
        float p[4];
        #pragma unroll
        for (int r = 0; r < 4; r++) {
          float a_ = (accS[nt][r] + boff[nt][r]) + bias0;
          p[r] = (nt * 16 + fg * 4 + r <= lim) ? __expf(a_) : 0.0f;
        }
        lt += (p[0] + p[1]) + (p[2] + p[3]);
        u32 w0 = pk2(p[0], p[1]), w1 = pk2(p[2], p[3]);
        if (nt < 2) { P0.u[nt * 2] = w0; P0.u[nt * 2 + 1] = w1; }
        else        { P1.u[(nt - 2) * 2] = w0; P1.u[(nt - 2) * 2 + 1] = w1; }
      }
    }
    lp += lt;
    // O^T += V^T P^T (permuted k-space baked into VTp)
    #pragma unroll
    for (int nt = 0; nt < 4; nt++) {
      bf16x8 vf0 = *(const bf16x8*)&Vs0[(nt * 16 + fm) * 32 + fg * 8];
      accO[nt] = __builtin_amdgcn_mfma_f32_16x16x32_bf16(vf0, P0.v, accO[nt], 0, 0, 0);
      bf16x8 vf1 = *(const bf16x8*)&Vs1[(nt * 16 + fm) * 32 + fg * 8];
      accO[nt] = __builtin_amdgcn_mfma_f32_16x16x32_bf16(vf1, P1.v, accO[nt], 0, 0, 0);
    }
  }
  lp += __shfl_xor(lp, 16, 64);
  lp += __shfl_xor(lp, 32, 64);
  // slot: [q 64][d 64] bf16 + l fp32[64]
  u16* P = partials + ((size_t)bh * NSEG_ + blockIdx.x) * 4224;
  int sq = wv * 16 + fm;
  #pragma unroll
  for (int nt = 0; nt < 4; nt++) {
    uint2 ow;
    ow.x = pk2(accO[nt][0], accO[nt][1]);
    ow.y = pk2(accO[nt][2], accO[nt][3]);
    *(uint2*)(P + sq * 64 + nt * 16 + fg * 4) = ow;
  }
  if (fg == 0) *(float*)(P + 4096 + 2 * sq) = lp;
}

// ---------------- combine partials -> AO (b,n,h,d) ----------------
__global__ __launch_bounds__(256) void comb_k(const u16* __restrict__ partials,
                                              u16* __restrict__ AO) {
  int qt = blockIdx.x, bh = blockIdx.y, b = bh >> 4, h = bh & 15;
  int t = threadIdx.x, q = t >> 2, dq = (t & 3) * 16;
  int s = (qt + 9) >> 3;
  int cum = 0;
  for (int tt = qt + 1; tt < 32; tt++) cum += (tt + 9) >> 3;
  float acc[16] = {};
  float lsum = 0.0f;
  for (int k = 0; k < s; k++) {
    const u16* P = partials + ((size_t)bh * NSEG_ + cum + k) * 4224;
    uint4 a = *(const uint4*)(P + q * 64 + dq);
    uint4 bq = *(const uint4*)(P + q * 64 + dq + 8);
    float tmp[8];
    unp8(a, tmp);
    #pragma unroll
    for (int e = 0; e < 8; e++) acc[e] += tmp[e];
    unp8(bq, tmp);
    #pragma unroll
    for (int e = 0; e < 8; e++) acc[8 + e] += tmp[e];
    lsum += *(const float*)(P + 4096 + 2 * q);
  }
  float linv = 1.0f / lsum;
  int n = qt * 64 + q;
  u16* dst = AO + (((size_t)(b * N_ + n)) * H_ + h) * 64 + dq;
  u16 ov[16] __attribute__((aligned(16)));
  #pragma unroll
  for (int e = 0; e < 16; e++) ov[e] = f2b(acc[e] * linv);
  *(uint4*)dst = ((uint4*)ov)[0];
  *(uint4*)(dst + 8) = ((uint4*)ov)[1];
}

// ---------------- launch ----------------
extern "C" void kernel_launch(void* const* d_in, const int* in_sizes, int n_in,
                              void* d_out, int out_size, void* d_ws, size_t ws_size,
                              hipStream_t stream) {
  const float* x    = (const float*)d_in[0];
  const float* ng   = (const float*)d_in[1];
  const float* nb   = (const float*)d_in[2];
  const float* Wq   = (const float*)d_in[3];
  const float* Wkv  = (const float*)d_in[4];
  const float* qs   = (const float*)d_in[5];
  const float* ks   = (const float*)d_in[6];
  const float* nkv  = (const float*)d_in[7];
  const float* Wout = (const float*)d_in[8];
  float* out = (float*)d_out;
  char* ws = (char*)d_ws;

  // layout (bytes):
  u16* xn    = (u16*)(ws + 0);            // 8,388,608 (AO reuses after Q-GEMM)
  u16* WoutT = (u16*)(ws + 8388608);      // 2,097,152
  u16* Qn    = (u16*)(ws + 10485760);     // 8,388,608
  u16* Kb    = (u16*)(ws + 18874368);     // 8,650,752 (JP stride)
  u16* VTp   = (u16*)(ws + 27525120);     // 8,650,752
  // overlay region @36175872 (dead by attn time):
  u16* xbf   = (u16*)(ws + 36175872);     // 8,388,608  (dead after KV-GEMM)
  u16* WqT   = (u16*)(ws + 44564480);     // 2,097,152  (dead after Q-GEMM)
  u16* WkvT  = (u16*)(ws + 46661632);     // 4,194,304  (dead after KV-GEMM)
  u16* Vb    = (u16*)(ws + 50855936);     // 8,396,800  (dead after vtransp) end 59,252,736
  u16* parts = xbf;                       // 32*84*8448 = 22,708,224 (fits overlay)
  u16* AO    = xn;

  hipMemsetAsync(Kb, 0, 8650752, stream);   // zero JP tail rows
  ktranspose_cast<<<dim3(32, 32), 256, 0, stream>>>(Wq, WqT, 1024, 1024);
  ktranspose_cast<<<dim3(64, 32), 256, 0, stream>>>(Wkv, WkvT, 1024, 2048);
  ktranspose_cast<<<dim3(32, 32), 256, 0, stream>>>(Wout, WoutT, 1024, 1024);
  lnorm_k<<<4096, 256, 0, stream>>>(x, ng, nb, xn, xbf);
  gemm_k<2><<<dim3(8, 32), 256, 0, stream>>>(xn, WqT, Qn, nullptr, qs, M_, 1024, 1024);
  gemm_k<3><<<dim3(16, 32), 256, 0, stream>>>(xbf, WkvT, Kb, Vb, ks, M_, 2048, 1024);
  vtransp_k<<<dim3(33, 32), 256, 0, stream>>>(Vb, nkv, ks, Kb, VTp);
  attn_k<<<dim3(NSEG_, 32), 256, 0, stream>>>(Qn, Kb, VTp, qs, ks, parts);
  comb_k<<<dim3(32, 32), 256, 0, stream>>>(parts, AO);
  gemm_k<1><<<dim3(8, 32), 256, 0, stream>>>(AO, WoutT, out, nullptr, nullptr, M_, 1024, 1024);
}

// Round 7
// 231.267 us; speedup vs baseline: 1.2376x; 1.2376x over previous
//
#include <hip/hip_runtime.h>
#include <hip/hip_bf16.h>
#include <stdint.h>

// Problem constants
#define H_    16
#define N_    2048
#define DIM_  1024
#define DH_   64
#define NN_   2
#define J_    2050     // N + NNULL
#define JP_   2112     // 33*64, padded j (Kb zero tail via memset, VTp zero-filled)
#define B_    2
#define M_    4096     // B * N
#define NSEG_ 84       // sum over qt of ceil((qt+2)/8)

typedef unsigned short u16;
typedef unsigned int u32;
typedef short bf16x8 __attribute__((ext_vector_type(8)));
typedef float f32x4 __attribute__((ext_vector_type(4)));

__device__ __forceinline__ u16 f2b(float f) {
  union { float f; unsigned int i; } v; v.f = f;
  unsigned int r = v.i + 0x7fffu + ((v.i >> 16) & 1u);   // RNE
  return (u16)(r >> 16);
}
__device__ __forceinline__ float b2f(u16 u) {
  union { unsigned int i; float f; } v; v.i = ((unsigned int)u) << 16; return v.f;
}
__device__ __forceinline__ float lo2f(u32 u) {
  union { u32 i; float f; } v; v.i = u << 16; return v.f;
}
__device__ __forceinline__ float hi2f(u32 u) {
  union { u32 i; float f; } v; v.i = u & 0xffff0000u; return v.f;
}
__device__ __forceinline__ void unp8(const uint4 u, float* d) {
  d[0] = lo2f(u.x); d[1] = hi2f(u.x); d[2] = lo2f(u.y); d[3] = hi2f(u.y);
  d[4] = lo2f(u.z); d[5] = hi2f(u.z); d[6] = lo2f(u.w); d[7] = hi2f(u.w);
}
// packed fp32x2 -> bf16x2
__device__ __forceinline__ u32 pk2(float a, float b) {
  union { __hip_bfloat162 h; u32 u; } x;
  x.h = __float22bfloat162_rn(make_float2(a, b));
  return x.u;
}
// async global->LDS DMA, 16B/lane; LDS dest = wave-uniform base + lane*16
__device__ __forceinline__ void dma16(const u16* g, u16* l) {
  __builtin_amdgcn_global_load_lds(
      (const __attribute__((address_space(1))) u32*)(const void*)g,
      (__attribute__((address_space(3))) u32*)(void*)l, 16, 0, 0);
}

// ---------------- transpose + cast (fp32 R x C -> bf16 C x R) ----------------
__global__ __launch_bounds__(256) void ktranspose_cast(const float* __restrict__ in,
                                                       u16* __restrict__ out, int R, int C) {
  __shared__ float tile[32][33];
  int tx = threadIdx.x & 31, ty = threadIdx.x >> 5;   // 32 x 8
  int c0 = blockIdx.x * 32, r0 = blockIdx.y * 32;
  #pragma unroll
  for (int i = 0; i < 32; i += 8)
    tile[ty + i][tx] = in[(size_t)(r0 + ty + i) * C + c0 + tx];
  __syncthreads();
  #pragma unroll
  for (int i = 0; i < 32; i += 8)
    out[(size_t)(c0 + ty + i) * R + r0 + tx] = f2b(tile[tx][ty + i]);
}

// ---------- LayerNorm (fp32 in) -> xn (bf16 LN) + xbf (bf16 cast of x) ----------
__global__ __launch_bounds__(256) void lnorm_k(const float* __restrict__ x,
                                               const float* __restrict__ g,
                                               const float* __restrict__ bb,
                                               u16* __restrict__ xn,
                                               u16* __restrict__ xbf) {
  int row = blockIdx.x;
  int t = threadIdx.x;
  float4 rw = *(const float4*)(x + (size_t)row * DIM_ + t * 4);
  float v0 = rw.x, v1 = rw.y, v2 = rw.z, v3 = rw.w;
  uint2 cw;
  cw.x = pk2(v0, v1);
  cw.y = pk2(v2, v3);
  *(uint2*)(xbf + (size_t)row * DIM_ + t * 4) = cw;
  float s = v0 + v1 + v2 + v3;
  float ss = v0 * v0 + v1 * v1 + v2 * v2 + v3 * v3;
  #pragma unroll
  for (int o = 32; o; o >>= 1) { s += __shfl_xor(s, o, 64); ss += __shfl_xor(ss, o, 64); }
  __shared__ float red[8];
  int lane = t & 63, w = t >> 6;
  if (lane == 0) { red[w] = s; red[4 + w] = ss; }
  __syncthreads();
  float S = red[0] + red[1] + red[2] + red[3];
  float SS = red[4] + red[5] + red[6] + red[7];
  float mu = S * (1.0f / DIM_);
  float var = SS * (1.0f / DIM_) - mu * mu;
  float rs = rsqrtf(var + 1e-5f);
  float4 gv = *(const float4*)(g + t * 4);
  float4 bv = *(const float4*)(bb + t * 4);
  uint2 ow;
  ow.x = pk2((v0 - mu) * rs * gv.x + bv.x, (v1 - mu) * rs * gv.y + bv.y);
  ow.y = pk2((v2 - mu) * rs * gv.z + bv.z, (v3 - mu) * rs * gv.w + bv.w);
  *(uint2*)(xn + (size_t)row * DIM_ + t * 4) = ow;
}

// ---------------- MFMA GEMM, 128m x 64n tile, BK=64, swizzled LDS ----------------
// LDS slot for (row, kblk of 8 u16): row*64 + ((kblk ^ (row&7)) * 8)  -> conflict-free b128
// MODE 1: fp32 row-major -> dst0
// MODE 2: per-row l2norm over 64-col head * qs -> Qn (b,h,n,d)
// MODE 3: cols<1024: l2norm*ks -> Kb (stride JP); else bf16 -> Vb (stride J)
template <int MODE>
__global__ __launch_bounds__(256) void gemm_k(const u16* __restrict__ A,
                                              const u16* __restrict__ BT,
                                              void* __restrict__ dst0,
                                              void* __restrict__ dst1,
                                              const float* __restrict__ scale,
                                              int M, int Nc, int K) {
  __shared__ u16 As[128 * 64];   // 16 KB
  __shared__ u16 Bs[64 * 64];    //  8 KB
  int tid = threadIdx.x, wv = tid >> 6, lane = tid & 63;
  int fm = lane & 15, fg = lane >> 4;
  int row0 = blockIdx.y * 128, col0 = blockIdx.x * 64;
  f32x4 acc[2][4] = {};
  // staging geometry: one dma16 = 8 rows x 128B; lane i -> row i>>3, stored kblk i&7
  int srow = lane >> 3;                 // 0..7
  int skb = ((lane & 7) ^ srow) * 8;    // swizzled global k-offset (u16)
  const u16* Ag = A + (size_t)(row0 + wv * 32 + srow) * K + skb;
  const u16* Bg = BT + (size_t)(col0 + wv * 16 + srow) * K + skb;
  u16* AsW = As + (wv * 32) * 64;
  u16* BsW = Bs + (wv * 16) * 64;
  // frag read offsets (row&7 == fm&7 since row = mult16 + fm)
  int fr7 = fm & 7;
  int ak0 = (fg ^ fr7) * 8;            // k-half 0: kblk = fg
  int ak1 = ((fg + 4) ^ fr7) * 8;      // k-half 1: kblk = fg + 4
  for (int k0 = 0; k0 < K; k0 += 64) {
    __syncthreads();
    dma16(Ag + k0,                    AsW);
    dma16(Ag + (size_t)8 * K + k0,    AsW + 8 * 64);
    dma16(Ag + (size_t)16 * K + k0,   AsW + 16 * 64);
    dma16(Ag + (size_t)24 * K + k0,   AsW + 24 * 64);
    dma16(Bg + k0,                    BsW);
    dma16(Bg + (size_t)8 * K + k0,    BsW + 8 * 64);
    __syncthreads();
    bf16x8 af0[2], af1[2], bf0[4], bf1[4];
    #pragma unroll
    for (int mt = 0; mt < 2; mt++) {
      int rbase = (wv * 32 + mt * 16 + fm) * 64;
      af0[mt] = *(const bf16x8*)&As[rbase + ak0];
      af1[mt] = *(const bf16x8*)&As[rbase + ak1];
    }
    #pragma unroll
    for (int nt = 0; nt < 4; nt++) {
      int rbase = (nt * 16 + fm) * 64;
      bf0[nt] = *(const bf16x8*)&Bs[rbase + ak0];
      bf1[nt] = *(const bf16x8*)&Bs[rbase + ak1];
    }
    #pragma unroll
    for (int mt = 0; mt < 2; mt++)
      #pragma unroll
      for (int nt = 0; nt < 4; nt++) {
        acc[mt][nt] = __builtin_amdgcn_mfma_f32_16x16x32_bf16(af0[mt], bf0[nt], acc[mt][nt], 0, 0, 0);
        acc[mt][nt] = __builtin_amdgcn_mfma_f32_16x16x32_bf16(af1[mt], bf1[nt], acc[mt][nt], 0, 0, 0);
      }
  }
  // C/D layout per 16x16 tile: col = fm, row = fg*4 + r
  if (MODE == 1) {
    float* C = (float*)dst0;
    #pragma unroll
    for (int mt = 0; mt < 2; mt++)
      #pragma unroll
      for (int r = 0; r < 4; r++) {
        int m = row0 + wv * 32 + mt * 16 + fg * 4 + r;
        #pragma unroll
        for (int nt = 0; nt < 4; nt++)
          C[(size_t)m * Nc + col0 + nt * 16 + fm] = acc[mt][nt][r];
      }
  } else {
    bool isK = (MODE == 2) || (col0 < 1024);
    int h = (isK ? col0 : col0 - 1024) >> 6;
    float sv[4];
    if (isK) {
      #pragma unroll
      for (int nt = 0; nt < 4; nt++) sv[nt] = scale[nt * 16 + fm];
    }
    u16* Do = (u16*)((MODE == 3 && !isK) ? dst1 : dst0);
    #pragma unroll
    for (int mt = 0; mt < 2; mt++) {
      #pragma unroll
      for (int r = 0; r < 4; r++) {
        float inv = 1.0f;
        if (isK) {
          float ssp = 0.0f;
          #pragma unroll
          for (int nt = 0; nt < 4; nt++) ssp += acc[mt][nt][r] * acc[mt][nt][r];
          #pragma unroll
          for (int o = 1; o <= 8; o <<= 1) ssp += __shfl_xor(ssp, o, 64);
          inv = 1.0f / fmaxf(sqrtf(ssp), 1e-12f);
        }
        int m = row0 + wv * 32 + mt * 16 + fg * 4 + r;
        int b = m >> 11, n = m & 2047;
        size_t base;
        if (MODE == 2)      base = (((size_t)(b * H_ + h)) * N_ + n) * 64;
        else if (isK)       base = (((size_t)(b * H_ + h)) * JP_ + (n + NN_)) * 64;
        else                base = (((size_t)(b * H_ + h)) * J_ + (n + NN_)) * 64;
        #pragma unroll
        for (int nt = 0; nt < 4; nt++) {
          float val = acc[mt][nt][r];
          if (isK) val = val * inv * sv[nt];
          Do[base + nt * 16 + fm] = f2b(val);
        }
      }
    }
  }
}

// ------- V transpose+permute: Vb (b,h,j,d) + null kv -> VTp (b,h,d,pos); also Kb j<2 -------
// VTp[bh][d][c*64+pos] = V[bh][c*64 + pi(pos)][d],
// pi(pos): h2=pos>>5, fgp=(pos>>3)&3, nt=(pos>>2)&1, r=pos&3 -> j = (h2*2+nt)*16 + fgp*4 + r
__global__ __launch_bounds__(256) void vtransp_k(const u16* __restrict__ Vb,
                                                 const float* __restrict__ nkv,
                                                 const float* __restrict__ ks,
                                                 u16* __restrict__ Kb,
                                                 u16* __restrict__ VTp) {
  __shared__ u16 tile[64][80];
  int t = threadIdx.x;
  int c = blockIdx.x, bh = blockIdx.y, h = bh & 15;
  int jl = t >> 2, dc = (t & 3) * 16;
  int j = c * 64 + jl;
  if (j < NN_) {
    float kvv[16];
    float kssp = 0.0f;
    #pragma unroll
    for (int e = 0; e < 16; e++) {
      float vv = nkv[(size_t)(h * 4 + 2 * j + 1) * 64 + dc + e];
      tile[jl][dc + e] = f2b(vv);
      float kv = nkv[(size_t)(h * 4 + 2 * j) * 64 + dc + e];
      kvv[e] = kv; kssp += kv * kv;
    }
    kssp += __shfl_xor(kssp, 1, 64);
    kssp += __shfl_xor(kssp, 2, 64);
    float inv = 1.0f / fmaxf(sqrtf(kssp), 1e-12f);
    #pragma unroll
    for (int e = 0; e < 16; e++)
      Kb[((size_t)bh * JP_ + j) * 64 + dc + e] = f2b(kvv[e] * inv * ks[dc + e]);
  } else if (j < J_) {
    const uint4* src = (const uint4*)(Vb + ((size_t)bh * J_ + j) * 64 + dc);
    *(uint4*)&tile[jl][dc] = src[0];
    *(uint4*)&tile[jl][dc + 8] = src[1];
  } else {
    uint4 z = {0, 0, 0, 0};
    *(uint4*)&tile[jl][dc] = z;
    *(uint4*)&tile[jl][dc + 8] = z;
  }
  __syncthreads();
  int d = t >> 2, p0 = (t & 3) * 16;
  u16 tmp[16] __attribute__((aligned(16)));
  #pragma unroll
  for (int e = 0; e < 16; e++) {
    int pos = p0 + e;
    int h2 = pos >> 5, rem = pos & 31;
    int fgp = rem >> 3, tt = rem & 7;
    int nt = tt >> 2, r = tt & 3;
    int jloc = (h2 * 2 + nt) * 16 + fgp * 4 + r;
    tmp[e] = tile[jloc][d];
  }
  uint4* dstp = (uint4*)(VTp + ((size_t)bh * 64 + d) * JP_ + c * 64 + p0);
  dstp[0] = ((uint4*)tmp)[0];
  dstp[1] = ((uint4*)tmp)[1];
}

// ---------------- MFMA flash attention, j-SPLIT partial blocks (R5 body + swizzled LDS) -----
// LDS slot for (row, kblk of 8 u16, 4 kblks/row): row*32 + ((kblk ^ ((row>>1)&3)) * 8)
__global__ __launch_bounds__(256, 6) void attn_k(const u16* __restrict__ Qn,
                                                 const u16* __restrict__ Kb,
                                                 const u16* __restrict__ VTp,
                                                 const float* __restrict__ qs,
                                                 const float* __restrict__ ks,
                                                 u16* __restrict__ partials) {
  __shared__ u16 Ks0[64 * 32], Ks1[64 * 32];   // K chunk rows j, d 0..31 / 32..63
  __shared__ u16 Vs0[64 * 32], Vs1[64 * 32];   // V^T chunk rows d, j-pos 0..31 / 32..63
  int tid = threadIdx.x;
  int wv = tid >> 6, lane = tid & 63;
  int fm = lane & 15, fg = lane >> 4;
  int bh = blockIdx.y, h = bh & 15;
  // segment decode (qt descending)
  int cum = 0, qt = 0, seg = 0;
  #pragma unroll 1
  for (int i = 0; i < 32; i++) {
    int t = 31 - i, s = (t + 9) >> 3;
    if ((int)blockIdx.x < cum + s) { qt = t; seg = (int)blockIdx.x - cum; break; }
    cum += s;
  }
  int q0 = qt * 64;
  int q = q0 + wv * 16 + fm;
  float slope = exp2f(-0.5f * (float)(h + 1));
  float prod = fabsf(qs[lane] * ks[lane]);
  #pragma unroll
  for (int o = 32; o; o >>= 1) prod = fmaxf(prod, __shfl_xor(prod, o, 64));
  float Mb = 8.0f * prod;
  const u16* qp = Qn + ((size_t)bh * N_ + q) * 64 + fg * 8;
  bf16x8 qf0 = *(const bf16x8*)(qp);        // d 0..31 slice
  bf16x8 qf1 = *(const bf16x8*)(qp + 32);   // d 32..63 slice
  f32x4 accO[4] = {};
  float lp = 0.0f;
  int lr = lane >> 2;                                  // staging row 0..15
  int kbs = ((lane & 3) ^ ((lane >> 3) & 3)) * 8;      // swizzled staging k-offset
  int fs = (fg ^ ((fm >> 1) & 3)) * 8;                 // swizzled frag offset
  const u16* KbBH = Kb + (size_t)bh * JP_ * 64;
  const u16* VTbh = VTp + (size_t)bh * 64 * JP_;
  int c0 = seg * 8;
  int c1 = min(c0 + 8, qt + 2);
  for (int c = c0; c < c1; c++) {
    int jb = c * 64;
    __syncthreads();
    const u16* Kg = KbBH + (size_t)(jb + wv * 16 + lr) * 64 + kbs;
    dma16(Kg,      Ks0 + wv * 512);
    dma16(Kg + 32, Ks1 + wv * 512);
    const u16* Vg = VTbh + (size_t)(wv * 16 + lr) * JP_ + jb + kbs;
    dma16(Vg,      Vs0 + wv * 512);
    dma16(Vg + 32, Vs1 + wv * 512);
    __syncthreads();
    // S^T = K Q^T
    f32x4 accS[4] = {};
    #pragma unroll
    for (int nt = 0; nt < 4; nt++) {
      bf16x8 kf0 = *(const bf16x8*)&Ks0[(nt * 16 + fm) * 32 + fs];
      accS[nt] = __builtin_amdgcn_mfma_f32_16x16x32_bf16(kf0, qf0, accS[nt], 0, 0, 0);
      bf16x8 kf1 = *(const bf16x8*)&Ks1[(nt * 16 + fm) * 32 + fs];
      accS[nt] = __builtin_amdgcn_mfma_f32_16x16x32_bf16(kf1, qf1, accS[nt], 0, 0, 0);
    }
    // softmax in-register; pack P^T B-frags (k-space permutation matches VTp's pi)
    union { bf16x8 v; u16 s[8]; } P0, P1;
    #pragma unroll
    for (int nt = 0; nt < 4; nt++) {
      #pragma unroll
      for (int r = 0; r < 4; r++) {
        int jj = jb + nt * 16 + fg * 4 + r;
        float arg = fmaf(accS[nt][r], 8.0f, slope * (float)(jj - q - 2)) - Mb;
        float p = (jj <= q + 2) ? __expf(arg) : 0.0f;
        u16 pb = f2b(p);
        lp += b2f(pb);
        if (nt < 2) P0.s[nt * 4 + r] = pb;
        else        P1.s[(nt - 2) * 4 + r] = pb;
      }
    }
    // O^T += V^T P^T
    #pragma unroll
    for (int nt = 0; nt < 4; nt++) {
      bf16x8 vf0 = *(const bf16x8*)&Vs0[(nt * 16 + fm) * 32 + fs];
      accO[nt] = __builtin_amdgcn_mfma_f32_16x16x32_bf16(vf0, P0.v, accO[nt], 0, 0, 0);
      bf16x8 vf1 = *(const bf16x8*)&Vs1[(nt * 16 + fm) * 32 + fs];
      accO[nt] = __builtin_amdgcn_mfma_f32_16x16x32_bf16(vf1, P1.v, accO[nt], 0, 0, 0);
    }
  }
  lp += __shfl_xor(lp, 16, 64);
  lp += __shfl_xor(lp, 32, 64);
  // slot: [q 64][d 64] bf16 + l fp32[64]
  u16* P = partials + ((size_t)bh * NSEG_ + blockIdx.x) * 4224;
  int sq = wv * 16 + fm;
  #pragma unroll
  for (int nt = 0; nt < 4; nt++) {
    uint2 ow;
    ow.x = pk2(accO[nt][0], accO[nt][1]);
    ow.y = pk2(accO[nt][2], accO[nt][3]);
    *(uint2*)(P + sq * 64 + nt * 16 + fg * 4) = ow;
  }
  if (fg == 0) *(float*)(P + 4096 + 2 * sq) = lp;
}

// ---------------- combine partials -> AO (b,n,h,d) ----------------
__global__ __launch_bounds__(256) void comb_k(const u16* __restrict__ partials,
                                              u16* __restrict__ AO) {
  int qt = blockIdx.x, bh = blockIdx.y, b = bh >> 4, h = bh & 15;
  int t = threadIdx.x, q = t >> 2, dq = (t & 3) * 16;
  int s = (qt + 9) >> 3;
  int cum = 0;
  for (int tt = qt + 1; tt < 32; tt++) cum += (tt + 9) >> 3;
  float acc[16] = {};
  float lsum = 0.0f;
  for (int k = 0; k < s; k++) {
    const u16* P = partials + ((size_t)bh * NSEG_ + cum + k) * 4224;
    uint4 a = *(const uint4*)(P + q * 64 + dq);
    uint4 bq = *(const uint4*)(P + q * 64 + dq + 8);
    float tmp[8];
    unp8(a, tmp);
    #pragma unroll
    for (int e = 0; e < 8; e++) acc[e] += tmp[e];
    unp8(bq, tmp);
    #pragma unroll
    for (int e = 0; e < 8; e++) acc[8 + e] += tmp[e];
    lsum += *(const float*)(P + 4096 + 2 * q);
  }
  float linv = 1.0f / lsum;
  int n = qt * 64 + q;
  u16* dst = AO + (((size_t)(b * N_ + n)) * H_ + h) * 64 + dq;
  u16 ov[16] __attribute__((aligned(16)));
  #pragma unroll
  for (int e = 0; e < 16; e++) ov[e] = f2b(acc[e] * linv);
  *(uint4*)dst = ((uint4*)ov)[0];
  *(uint4*)(dst + 8) = ((uint4*)ov)[1];
}

// ---------------- launch ----------------
extern "C" void kernel_launch(void* const* d_in, const int* in_sizes, int n_in,
                              void* d_out, int out_size, void* d_ws, size_t ws_size,
                              hipStream_t stream) {
  const float* x    = (const float*)d_in[0];
  const float* ng   = (const float*)d_in[1];
  const float* nb   = (const float*)d_in[2];
  const float* Wq   = (const float*)d_in[3];
  const float* Wkv  = (const float*)d_in[4];
  const float* qs   = (const float*)d_in[5];
  const float* ks   = (const float*)d_in[6];
  const float* nkv  = (const float*)d_in[7];
  const float* Wout = (const float*)d_in[8];
  float* out = (float*)d_out;
  char* ws = (char*)d_ws;

  // layout (bytes):
  u16* xn    = (u16*)(ws + 0);            // 8,388,608 (AO reuses after Q-GEMM)
  u16* WoutT = (u16*)(ws + 8388608);      // 2,097,152
  u16* Qn    = (u16*)(ws + 10485760);     // 8,388,608
  u16* Kb    = (u16*)(ws + 18874368);     // 8,650,752 (JP stride)
  u16* VTp   = (u16*)(ws + 27525120);     // 8,650,752
  // overlay region @36175872 (dead by attn time):
  u16* xbf   = (u16*)(ws + 36175872);     // 8,388,608  (dead after KV-GEMM)
  u16* WqT   = (u16*)(ws + 44564480);     // 2,097,152  (dead after Q-GEMM)
  u16* WkvT  = (u16*)(ws + 46661632);     // 4,194,304  (dead after KV-GEMM)
  u16* Vb    = (u16*)(ws + 50855936);     // 8,396,800  (dead after vtransp) end 59,252,736
  u16* parts = xbf;                       // 32*84*8448 = 22,708,224 (fits overlay)
  u16* AO    = xn;

  hipMemsetAsync(Kb, 0, 8650752, stream);   // zero JP tail rows
  ktranspose_cast<<<dim3(32, 32), 256, 0, stream>>>(Wq, WqT, 1024, 1024);
  ktranspose_cast<<<dim3(64, 32), 256, 0, stream>>>(Wkv, WkvT, 1024, 2048);
  ktranspose_cast<<<dim3(32, 32), 256, 0, stream>>>(Wout, WoutT, 1024, 1024);
  lnorm_k<<<4096, 256, 0, stream>>>(x, ng, nb, xn, xbf);
  gemm_k<2><<<dim3(16, 32), 256, 0, stream>>>(xn, WqT, Qn, nullptr, qs, M_, 1024, 1024);
  gemm_k<3><<<dim3(32, 32), 256, 0, stream>>>(xbf, WkvT, Kb, Vb, ks, M_, 2048, 1024);
  vtransp_k<<<dim3(33, 32), 256, 0, stream>>>(Vb, nkv, ks, Kb, VTp);
  attn_k<<<dim3(NSEG_, 32), 256, 0, stream>>>(Qn, Kb, VTp, qs, ks, parts);
  comb_k<<<dim3(32, 32), 256, 0, stream>>>(parts, AO);
  gemm_k<1><<<dim3(16, 32), 256, 0, stream>>>(AO, WoutT, out, nullptr, nullptr, M_, 1024, 1024);
}